// Round 4
// baseline (605.954 us; speedup 1.0000x reference)
//
#include <hip/hip_runtime.h>
#include <hip/hip_cooperative_groups.h>
#include <math.h>

namespace cg = cooperative_groups;

// ONE RAY PER THREAD, SINGLE FUSED COOPERATIVE KERNEL (R11).
// R3 forensics: per-SIMD ray-parallelism is structurally pinned at 2
// (131072 rays / 65536 lane-slots) -- tpr=1 doubling waves changed nothing
// (79.0 -> 80.6 us, VALUBusy pinned ~48%). nerf_main is wedged at ~80 us.
// BUT: total dur (131-137) minus nerf_main (79-85) = a CONSTANT ~52 us of
// memset + norm-kernel + inter-dispatch gaps -- 40% of wall clock. This round
// fuses all three dispatches into one cooperative launch: init mmx in-kernel,
// grid.sync(), atomicMin, grid.sync(), normalize rdep IN REGISTER and store
// once (also deletes the norm kernel's 0.5MB read + rewrite).
// Co-residency: 2048 blocks x 1 wave, LDS 16.9KB -> 9 blocks/CU, VGPR 68 ->
// 2048 <= 2304 max cooperative grid. Compute phases are IDENTICAL to R3
// (exp2 geometric recurrence on the uniform coarse grid, zero exp2 in phases
// 1+2; phase 3 depths data-dependent -> full sigmoids; branchless machines,
// zero barriers, fd columns per-thread).

#define NT 64
#define PTS 64
#define NRAYS (2*256*256)
#define NEARV 0.1f
#define STEPV (1.9f/63.0f)
#define FAR63 (0.1f + 63.0f*(1.9f/63.0f))
#define NL2E (-1.4426950408889634f)

__device__ __forceinline__ float sig_pm(float arg) {   // arg is already -x*log2e
    return __builtin_amdgcn_rcpf(1.0f + __builtin_amdgcn_exp2f(arg));
}
__device__ __forceinline__ float sig_e(float e) {      // e = exp2(-x*log2e)
    return __builtin_amdgcn_rcpf(1.0f + e);
}

__global__ __launch_bounds__(NT, 2) void nerf_main(
    const float* __restrict__ tm, const float* __restrict__ wq,
    float* __restrict__ out, unsigned int* __restrict__ mmx)
{
    __shared__ float fd[PTS + 1][NT];      // per-ray fine depths + junk pad row
    const int tid = threadIdx.x;
    const int r = blockIdx.x * NT + tid;
    const int b = r >> 16, n = r & 65535;
    const int i = n >> 8, j = n & 255;

    // init the two min-keys (every block writes the same value; the grid.sync
    // before the atomics orders all inits before any atomicMin)
    if (tid == 0) {
        __hip_atomic_store(&mmx[0], 0xFFFFFFFFu, __ATOMIC_RELAXED, __HIP_MEMORY_SCOPE_AGENT);
        __hip_atomic_store(&mmx[1], 0xFFFFFFFFu, __ATOMIC_RELAXED, __HIP_MEMORY_SCOPE_AGENT);
    }

    float bA[4], sA[4];                    // feat[c]*(-log2e) = bA + d*sA
    {
        float cx = (1.0f + (float)j * (-2.0f/255.0f)) * (1.0f/4.2f);
        float cy = (1.0f + (float)i * (-2.0f/255.0f)) * (1.0f/4.2f);
        const float* tmb = tm + b*12;
        float dx = tmb[0]*cx + tmb[1]*cy + tmb[2];
        float dy = tmb[4]*cx + tmb[5]*cy + tmb[6];
        float dz = tmb[8]*cx + tmb[9]*cy + tmb[10];
        float ox = tmb[3], oy = tmb[7], oz = tmb[11];
        #pragma unroll
        for (int c = 0; c < 4; c++) {
            float s  = dx*wq[0*4+c] + dy*wq[1*4+c] + dz*wq[2*4+c];
            float bv = ox*wq[0*4+c] + oy*wq[1*4+c] + oz*wq[2*4+c]
                     + dx*wq[3*4+c] + dy*wq[4*4+c] + dz*wq[5*4+c];
            sA[c] = s * NL2E;
            bA[c] = bv * NL2E;
        }
    }

    // recurrence state: eV[c] = exp2(bA + d*sA) at the current coarse point,
    // kV[c] = per-step ratio exp2(sA*STEP). e00 = eV[0] at d = NEAR.
    float eV[4], kV[4], e00;
    #pragma unroll
    for (int c = 0; c < 4; c++) {
        eV[c] = __builtin_amdgcn_exp2f(bA[c] + NEARV*sA[c]);
        kV[c] = __builtin_amdgcn_exp2f(sA[c]*STEPV);
    }
    e00 = eV[0];

    // ---- phase 1: coarse march, zero exp2 ----
    float T = 1.0f, S = 0.0f;
    float a0 = 0.0f, a1 = 0.0f, a2 = 0.0f;
    #pragma unroll 4
    for (int p = 0; p < PTS; p++) {
        float op = sig_e(eV[0]);
        float v0 = sig_e(eV[1]);
        float v1 = sig_e(eV[2]);
        float v2 = sig_e(eV[3]);
        eV[0] *= kV[0];
        eV[1] *= kV[1];
        eV[2] *= kV[2];
        eV[3] *= kV[3];
        float w  = op * T;
        a0 = fmaf(w, v0, a0);
        a1 = fmaf(w, v1, a1);
        a2 = fmaf(w, v2, a2);
        S += w + 1e-5f;
        T *= (1.0f - op);
    }
    out[(b*3+0)*65536 + n] = a0;
    out[(b*3+1)*65536 + n] = a1;
    out[(b*3+2)*65536 + n] = a2;

    // ---- phase 2: branchless sampling machine, zero exp2 ----
    // eP tracks exp2-value at coarse index m = min(ind+1, 63); advance is one
    // conditional multiply by kV[0].
    float Sinv = __builtin_amdgcn_rcpf(S);
    float op0  = sig_e(e00);                 // sigmoid at d = NEAR (index 0)
    float T2   = 1.0f - op0;
    float c_lo = 0.0f;
    float c_hi = (op0 + 1e-5f) * Sinv;       // cdf[0]
    int ind = 0, kk = 1;
    float bin_prev = NEARV;                  // bin_0 == NEAR always
    float eP = e00 * kV[0];                  // index m = 1
    #pragma unroll 2
    for (int it = 0; it < 2*PTS; it++) {
        float u = (float)kk * 0.015625f;             // exact k/64
        bool adv = (ind < PTS) && (c_hi <= u);       // searchsorted 'right'
        float opn = sig_e(eP);                       // sigmoid at index m
        float wn  = opn * T2;
        float d0  = fmaf((float)(ind - 1), STEPV, NEARV);
        float den = c_hi - c_lo;
        den = (den < 1e-8f) ? 1.0f : den;            // ref guard
        float t = (u - c_lo) * __builtin_amdgcn_rcpf(den);
        t = fminf(fmaxf(t, 0.0f), 1.0f);
        float bin = fmaf(t, STEPV, d0);
        bin = (ind <= 0)   ? NEARV : bin;
        bin = (ind >= PTS) ? FAR63 : bin;
        float fdep = 0.5f * (bin_prev + bin);
        int widx = adv ? PTS : min(kk - 1, PTS);     // pad row on advance
        fd[widx][tid] = fdep;                        // unconditional ds_write
        float nc_hi = c_hi + (wn + 1e-5f) * Sinv;
        float nT2   = T2 * (1.0f - opn);
        // m = min(ind+1,63) increments iff adv && ind < 62
        float km    = (adv && (ind < 62)) ? kV[0] : 1.0f;
        c_lo     = adv ? c_hi : c_lo;
        c_hi     = adv ? nc_hi : c_hi;
        T2       = adv ? nT2 : T2;
        bin_prev = adv ? bin_prev : bin;
        eP      *= km;
        ind += adv ? 1 : 0;
        kk  += adv ? 0 : 1;
    }

    // ---- phase 3: branchless merge ----
    float T3 = 1.0f, sw = 0.0f;
    float f0 = 0.0f, f1 = 0.0f, f2 = 0.0f;
    float rd = 0.0f;
    int pc = 0, pf = 0;
    float dc = NEARV;
    float cur = fd[0][tid], nxt = fd[1][tid];
    #pragma unroll 2
    for (int it = 0; it < 2*PTS; it++) {
        float dfv = (pf < PTS) ? cur : 3.0e38f;
        bool tc = (pc < PTS) && (dc <= dfv);         // ties -> coarse (stable)
        float d = tc ? dc : dfv;
        pc += tc ? 1 : 0;
        dc = fmaf((float)pc, STEPV, NEARV);
        pf += tc ? 0 : 1;
        cur = tc ? cur : nxt;
        nxt = fd[min(pf + 1, PTS)][tid];             // unconditional ds_read
        float op = sig_pm(bA[0] + d*sA[0]);
        float v0 = sig_pm(bA[1] + d*sA[1]);
        float v1 = sig_pm(bA[2] + d*sA[2]);
        float v2 = sig_pm(bA[3] + d*sA[3]);
        float w  = op * T3;
        f0 = fmaf(w, v0, f0);
        f1 = fmaf(w, v1, f1);
        f2 = fmaf(w, v2, f2);
        sw += w;
        rd = fmaf(w, d, rd);
        T3 *= (1.0f - op);
    }

    out[393216 + (b*3+0)*65536 + n] = f0;
    out[393216 + (b*3+1)*65536 + n] = f1;
    out[393216 + (b*3+2)*65536 + n] = f2;
    float fop  = fminf(fmaxf(sw, 0.0f), 1.0f);
    float rdep = rd + (1.0f - fop) * 2.0f;           // d_all.max() == 2.0 exactly

    unsigned ub  = __float_as_uint(rdep);            // rdep>0: u32 order == float order
    unsigned kmn = ub;
    unsigned kmx = ~ub;
    #pragma unroll
    for (int m = 32; m >= 1; m >>= 1) {
        unsigned omn = (unsigned)__shfl_xor((int)kmn, m, 64);
        unsigned omx = (unsigned)__shfl_xor((int)kmx, m, 64);
        kmn = (omn < kmn) ? omn : kmn;
        kmx = (omx < kmx) ? omx : kmx;
    }

    // grid-wide min/max reduction + in-register normalize (fused tail)
    cg::this_grid().sync();                          // all inits + rdeps done
    if (tid == 0) {
        atomicMin(&mmx[0], kmn);
        atomicMin(&mmx[1], kmx);
    }
    cg::this_grid().sync();                          // all atomics visible
    unsigned umn = __hip_atomic_load(&mmx[0], __ATOMIC_RELAXED, __HIP_MEMORY_SCOPE_AGENT);
    unsigned umx = __hip_atomic_load(&mmx[1], __ATOMIC_RELAXED, __HIP_MEMORY_SCOPE_AGENT);
    float mn = __uint_as_float(umn);
    float mx = __uint_as_float(~umx);
    out[786432 + r] = (rdep - mn) * __builtin_amdgcn_rcpf(mx - mn);
}

extern "C" void kernel_launch(void* const* d_in, const int* in_sizes, int n_in,
                              void* d_out, int out_size, void* d_ws, size_t ws_size,
                              hipStream_t stream) {
    (void)in_sizes; (void)n_in; (void)out_size; (void)ws_size;
    const float* tm = (const float*)d_in[0];
    const float* wq = (const float*)d_in[1];
    float* out = (float*)d_out;
    unsigned int* mmx = (unsigned int*)d_ws;
    void* kargs[] = {(void*)&tm, (void*)&wq, (void*)&out, (void*)&mmx};
    hipLaunchCooperativeKernel((const void*)nerf_main, dim3(NRAYS/NT), dim3(NT),
                               kargs, 0, stream);
}

// Round 5
// 173.958 us; speedup vs baseline: 3.4833x; 3.4833x over previous
//
#include <hip/hip_runtime.h>
#include <math.h>

// TWO LANES PER RAY (R12). R4 post-mortem: grid.sync() costs ~250us/sync on
// MI355X (FETCH 365MB of spin-poll misses) -- cooperative fusion reverted.
// Consolidated R0-R3 model: VALUBusy pinned ~48% because the chip hosts
// exactly 2 independent ray-streams per SIMD (131072 rays / 65536 lane-slots),
// each ~24% issue duty limited by its serial dependency chain. More streams
// need more THREADS PER RAY. Transmittance factorizes (accumulators linear in
// T-start), so: lane pair (2t,2t+1) splits each ray's marches:
//  - phase 1: 32 coarse pts per lane + shfl_xor(1) fixup (serial len halved)
//  - phase 2: unsplittable serial machine -> unchanged, runs on even lanes
//  - phase 3: merge-path diagonal search at 64 (exact comparator -> take
//    decisions bit-identical to R3), 64 its per lane, linear T3 fixup.
// 262144 threads = 4096 waves = 4 streams/SIMD. fd re-laid [65][32]: bank =
// ray-id -> <=2-way (free). 8.3KB/block x16 blocks/CU = 133KB <= 160.
// launch_bounds(64,4) caps VGPR at 128 so 16 blocks/CU fit.
// R9 recurrence numerics kept; product-reorder drift ~1e-6 (continuous);
// absmax was a rock-solid 0.00390625 across R0-R3 variants.

#define NT 64
#define PTS 64
#define NRAYS (2*256*256)
#define NEARV 0.1f
#define STEPV (1.9f/63.0f)
#define FAR63 (0.1f + 63.0f*(1.9f/63.0f))
#define NL2E (-1.4426950408889634f)

__device__ __forceinline__ float sig_pm(float arg) {   // arg is already -x*log2e
    return __builtin_amdgcn_rcpf(1.0f + __builtin_amdgcn_exp2f(arg));
}
__device__ __forceinline__ float sig_e(float e) {      // e = exp2(-x*log2e)
    return __builtin_amdgcn_rcpf(1.0f + e);
}

__global__ __launch_bounds__(NT, 4) void nerf_main(
    const float* __restrict__ tm, const float* __restrict__ wq,
    float* __restrict__ out, unsigned int* __restrict__ mmx)
{
    __shared__ float fd[PTS + 1][32];      // [depth-idx][ray-local]: bank = rl
    const int tid = threadIdx.x;
    const int g  = blockIdx.x * NT + tid;
    const int r  = g >> 1;                 // ray index
    const int h  = g & 1;                  // half: 0 = pts 0..31, 1 = pts 32..63
    const int rl = tid >> 1;               // ray-local index (0..31)
    const int b = r >> 16, n = r & 65535;
    const int i = n >> 8, j = n & 255;

    float bA[4], sA[4];                    // feat[c]*(-log2e) = bA + d*sA
    {
        float cx = (1.0f + (float)j * (-2.0f/255.0f)) * (1.0f/4.2f);
        float cy = (1.0f + (float)i * (-2.0f/255.0f)) * (1.0f/4.2f);
        const float* tmb = tm + b*12;
        float dx = tmb[0]*cx + tmb[1]*cy + tmb[2];
        float dy = tmb[4]*cx + tmb[5]*cy + tmb[6];
        float dz = tmb[8]*cx + tmb[9]*cy + tmb[10];
        float ox = tmb[3], oy = tmb[7], oz = tmb[11];
        #pragma unroll
        for (int c = 0; c < 4; c++) {
            float s  = dx*wq[0*4+c] + dy*wq[1*4+c] + dz*wq[2*4+c];
            float bv = ox*wq[0*4+c] + oy*wq[1*4+c] + oz*wq[2*4+c]
                     + dx*wq[3*4+c] + dy*wq[4*4+c] + dz*wq[5*4+c];
            sA[c] = s * NL2E;
            bA[c] = bv * NL2E;
        }
    }

    // recurrence consts; each lane starts its half at its own depth
    float kV[4], eV[4];
    float e00 = __builtin_amdgcn_exp2f(bA[0] + NEARV*sA[0]);
    float dstart = h ? fmaf(32.0f, STEPV, NEARV) : NEARV;
    #pragma unroll
    for (int c = 0; c < 4; c++) {
        kV[c] = __builtin_amdgcn_exp2f(sA[c]*STEPV);
        eV[c] = __builtin_amdgcn_exp2f(bA[c] + dstart*sA[c]);
    }

    // ---- phase 1: coarse march, 32 pts per lane, zero exp2 ----
    float T = 1.0f, Sw = 0.0f;
    float a0 = 0.0f, a1 = 0.0f, a2 = 0.0f;
    #pragma unroll 4
    for (int p = 0; p < 32; p++) {
        float op = sig_e(eV[0]);
        float v0 = sig_e(eV[1]);
        float v1 = sig_e(eV[2]);
        float v2 = sig_e(eV[3]);
        eV[0] *= kV[0];
        eV[1] *= kV[1];
        eV[2] *= kV[2];
        eV[3] *= kV[3];
        float w  = op * T;
        a0 = fmaf(w, v0, a0);
        a1 = fmaf(w, v1, a1);
        a2 = fmaf(w, v2, a2);
        Sw += w;
        T *= (1.0f - op);
    }
    // pair fixup: full = A_half + T_midA * B_half  (accumulators linear in T)
    float oT = __shfl_xor(T, 1, 64);
    float oS = __shfl_xor(Sw, 1, 64);
    float o0 = __shfl_xor(a0, 1, 64);
    float o1 = __shfl_xor(a1, 1, 64);
    float o2 = __shfl_xor(a2, 1, 64);
    float T_mid  = h ? oT : T;
    float Sfull  = (h ? oS : Sw) + T_mid * (h ? Sw : oS) + 64.0f*1e-5f;
    float A0 = (h ? o0 : a0) + T_mid * (h ? a0 : o0);
    float A1 = (h ? o1 : a1) + T_mid * (h ? a1 : o1);
    float A2 = (h ? o2 : a2) + T_mid * (h ? a2 : o2);
    if (h == 0) {
        out[(b*3+0)*65536 + n] = A0;
        out[(b*3+1)*65536 + n] = A1;
        out[(b*3+2)*65536 + n] = A2;
    }

    // ---- phase 2: branchless sampling machine (even lanes), zero exp2 ----
    float Sinv = __builtin_amdgcn_rcpf(Sfull);
    if (h == 0) {
        float op0 = sig_e(e00);
        float T2   = 1.0f - op0;
        float c_lo = 0.0f;
        float c_hi = (op0 + 1e-5f) * Sinv;       // cdf[0]
        int ind = 0, kk = 1;
        float bin_prev = NEARV;                  // bin_0 == NEAR always
        float eP = e00 * kV[0];                  // index m = 1
        #pragma unroll 2
        for (int it = 0; it < 2*PTS; it++) {
            float u = (float)kk * 0.015625f;             // exact k/64
            bool adv = (ind < PTS) && (c_hi <= u);       // searchsorted 'right'
            float opn = sig_e(eP);                       // sigmoid at index m
            float wn  = opn * T2;
            float d0  = fmaf((float)(ind - 1), STEPV, NEARV);
            float den = c_hi - c_lo;
            den = (den < 1e-8f) ? 1.0f : den;            // ref guard
            float t = (u - c_lo) * __builtin_amdgcn_rcpf(den);
            t = fminf(fmaxf(t, 0.0f), 1.0f);
            float bin = fmaf(t, STEPV, d0);
            bin = (ind <= 0)   ? NEARV : bin;
            bin = (ind >= PTS) ? FAR63 : bin;
            float fdep = 0.5f * (bin_prev + bin);
            int widx = adv ? PTS : min(kk - 1, PTS);     // pad row on advance
            fd[widx][rl] = fdep;                         // unconditional ds_write
            float nc_hi = c_hi + (wn + 1e-5f) * Sinv;
            float nT2   = T2 * (1.0f - opn);
            float km    = (adv && (ind < 62)) ? kV[0] : 1.0f;
            c_lo     = adv ? c_hi : c_lo;
            c_hi     = adv ? nc_hi : c_hi;
            T2       = adv ? nT2 : T2;
            bin_prev = adv ? bin_prev : bin;
            eP      *= km;
            ind += adv ? 1 : 0;
            kk  += adv ? 0 : 1;
        }
    }
    __syncthreads();

    // ---- phase 3: branchless merge, 64 its per lane ----
    // odd lane finds its start via merge-path diagonal 64: largest ii in
    // [0,64] with P(ii) = (ii==0) || coarse(ii-1) <= fine(64-ii). Comparator
    // identical to the walk's (coarse taken when dc <= dfv) -> exact split.
    int pc, pf;
    if (h) {
        int lo = 0, hi = 64;
        #pragma unroll
        for (int s = 0; s < 7; s++) {
            int mid = (lo + hi + 1) >> 1;
            float cd = fmaf((float)(mid - 1), STEPV, NEARV);
            float fv = fd[64 - mid][rl];     // mid==0 -> pad row, overridden
            bool p = (mid == 0) || (cd <= fv);
            lo = p ? mid : lo;
            hi = p ? hi : mid - 1;
        }
        pc = lo; pf = 64 - lo;
    } else {
        pc = 0; pf = 0;
    }
    float dc  = fmaf((float)pc, STEPV, NEARV);
    float cur = fd[min(pf, PTS)][rl];
    float nxt = fd[min(pf + 1, PTS)][rl];
    float T3 = 1.0f, sw = 0.0f;
    float f0 = 0.0f, f1 = 0.0f, f2 = 0.0f;
    float rd = 0.0f;
    #pragma unroll 2
    for (int it = 0; it < PTS; it++) {
        float dfv = (pf < PTS) ? cur : 3.0e38f;
        bool tc = (pc < PTS) && (dc <= dfv);         // ties -> coarse (stable)
        float d = tc ? dc : dfv;
        pc += tc ? 1 : 0;
        dc = fmaf((float)pc, STEPV, NEARV);
        pf += tc ? 0 : 1;
        cur = tc ? cur : nxt;
        nxt = fd[min(pf + 1, PTS)][rl];              // unconditional ds_read
        float op = sig_pm(bA[0] + d*sA[0]);
        float v0 = sig_pm(bA[1] + d*sA[1]);
        float v1 = sig_pm(bA[2] + d*sA[2]);
        float v2 = sig_pm(bA[3] + d*sA[3]);
        float w  = op * T3;
        f0 = fmaf(w, v0, f0);
        f1 = fmaf(w, v1, f1);
        f2 = fmaf(w, v2, f2);
        sw += w;
        rd = fmaf(w, d, rd);
        T3 *= (1.0f - op);
    }
    // pair fixup (linear in T3-start); symmetric -> both lanes get same value
    float q3 = __shfl_xor(T3, 1, 64);
    float qs = __shfl_xor(sw, 1, 64);
    float q0 = __shfl_xor(f0, 1, 64);
    float q1 = __shfl_xor(f1, 1, 64);
    float q2 = __shfl_xor(f2, 1, 64);
    float qr = __shfl_xor(rd, 1, 64);
    float TA  = h ? q3 : T3;
    float swF = (h ? qs : sw) + TA * (h ? sw : qs);
    float f0F = (h ? q0 : f0) + TA * (h ? f0 : q0);
    float f1F = (h ? q1 : f1) + TA * (h ? f1 : q1);
    float f2F = (h ? q2 : f2) + TA * (h ? f2 : q2);
    float rdF = (h ? qr : rd) + TA * (h ? rd : qr);
    if (h == 0) {
        out[393216 + (b*3+0)*65536 + n] = f0F;
        out[393216 + (b*3+1)*65536 + n] = f1F;
        out[393216 + (b*3+2)*65536 + n] = f2F;
    }
    float fop  = fminf(fmaxf(swF, 0.0f), 1.0f);
    float rdep = rdF + (1.0f - fop) * 2.0f;          // d_all.max() == 2.0 exactly
    if (h == 0) out[786432 + r] = rdep;

    unsigned ub  = __float_as_uint(rdep);            // rdep>0: u32 order == float order
    unsigned kmn = ub;                               // pairs duplicate: harmless for min
    unsigned kmx = ~ub;
    #pragma unroll
    for (int m = 32; m >= 1; m >>= 1) {
        unsigned omn = (unsigned)__shfl_xor((int)kmn, m, 64);
        unsigned omx = (unsigned)__shfl_xor((int)kmx, m, 64);
        kmn = (omn < kmn) ? omn : kmn;
        kmx = (omx < kmx) ? omx : kmx;
    }
    if (tid == 0) {
        atomicMin(&mmx[0], kmn);
        atomicMin(&mmx[1], kmx);
    }
}

__global__ __launch_bounds__(256) void nerf_norm(float* __restrict__ out,
                                                 const unsigned int* __restrict__ mmx)
{
    int idx = blockIdx.x * 256 + threadIdx.x;
    float mn = __uint_as_float(mmx[0]);
    float mx = __uint_as_float(~mmx[1]);
    float v = out[786432 + idx];
    out[786432 + idx] = (v - mn) * __builtin_amdgcn_rcpf(mx - mn);
}

extern "C" void kernel_launch(void* const* d_in, const int* in_sizes, int n_in,
                              void* d_out, int out_size, void* d_ws, size_t ws_size,
                              hipStream_t stream) {
    (void)in_sizes; (void)n_in; (void)out_size; (void)ws_size;
    const float* tm = (const float*)d_in[0];
    const float* wq = (const float*)d_in[1];
    float* out = (float*)d_out;
    unsigned int* mmx = (unsigned int*)d_ws;
    hipMemsetAsync(d_ws, 0xFF, 8, stream);     // both min-keys -> UINT_MAX
    nerf_main<<<(2*NRAYS)/NT, NT, 0, stream>>>(tm, wq, out, mmx);
    nerf_norm<<<NRAYS/256, 256, 0, stream>>>(out, mmx);
}

// Round 6
// 103.222 us; speedup vs baseline: 5.8704x; 1.6853x over previous
//
#include <hip/hip_runtime.h>
#include <math.h>

// ONE RAY PER THREAD, OFF-CHAIN SIGMOIDS (R13). R5 (2-lane split) regressed by
// duplicating phase-2 issue across 2x waves (+40us) -- reverted; it also gave
// the phase budget: ph2 ~40us, ph1+3 ~40us of the 80us wall. R0/R3/R5 pin
// VALUBusy at 48% regardless of occupancy: wall = per-SIMD issue + carried
// chains. The chains run THROUGH the sigmoids: T *= (1-op) with op=rcp(1+e)
// puts exp->add->rcp latency on the carried path every iteration.
// This round removes trans ops from ALL carried chains algebraically:
//  - phases 1,3: 1-op = e*rcp(1+e) -> T *= m, m off-chain; chain = 1 v_mul.
//    (e clamped to 1e37: inf -> m~1, op~0, same graceful behavior as before)
//  - phase 2: speculative opnB = rcp(1+eP*k) computed off-chain one iteration
//    early; next iteration SELECTS opn instead of computing it.
//  - dispatch diet: per-block min/max -> plain stores to a 2048-pair ws array
//    (no atomics -> no memset -> first-run safe); norm reduces the array.
//    3 dispatches -> 2.
// R9 recurrence numerics kept (zero exp2 in phases 1+2); phase 3 depths are
// data-dependent -> full (off-chain) sigmoids. Branchless machines, zero
// barriers, fd columns per-thread. LDS 16.6KB -> 8 blocks/CU = 2 waves/SIMD.

#define NT 64
#define PTS 64
#define NRAYS (2*256*256)
#define NEARV 0.1f
#define STEPV (1.9f/63.0f)
#define FAR63 (0.1f + 63.0f*(1.9f/63.0f))
#define NL2E (-1.4426950408889634f)
#define ECLAMP 1.0e37f

__global__ __launch_bounds__(NT, 2) void nerf_main(
    const float* __restrict__ tm, const float* __restrict__ wq,
    float* __restrict__ out, unsigned int* __restrict__ bmm)
{
    __shared__ float fd[PTS + 1][NT];      // per-ray fine depths + junk pad row
    const int tid = threadIdx.x;
    const int r = blockIdx.x * NT + tid;
    const int b = r >> 16, n = r & 65535;
    const int i = n >> 8, j = n & 255;

    float bA[4], sA[4];                    // feat[c]*(-log2e) = bA + d*sA
    {
        float cx = (1.0f + (float)j * (-2.0f/255.0f)) * (1.0f/4.2f);
        float cy = (1.0f + (float)i * (-2.0f/255.0f)) * (1.0f/4.2f);
        const float* tmb = tm + b*12;
        float dx = tmb[0]*cx + tmb[1]*cy + tmb[2];
        float dy = tmb[4]*cx + tmb[5]*cy + tmb[6];
        float dz = tmb[8]*cx + tmb[9]*cy + tmb[10];
        float ox = tmb[3], oy = tmb[7], oz = tmb[11];
        #pragma unroll
        for (int c = 0; c < 4; c++) {
            float s  = dx*wq[0*4+c] + dy*wq[1*4+c] + dz*wq[2*4+c];
            float bv = ox*wq[0*4+c] + oy*wq[1*4+c] + oz*wq[2*4+c]
                     + dx*wq[3*4+c] + dy*wq[4*4+c] + dz*wq[5*4+c];
            sA[c] = s * NL2E;
            bA[c] = bv * NL2E;
        }
    }

    // recurrence state: eV[c] = exp2(bA + d*sA) at the current coarse point,
    // kV[c] = per-step ratio exp2(sA*STEP). e00 = eV[0] at d = NEAR.
    float eV[4], kV[4], e00;
    #pragma unroll
    for (int c = 0; c < 4; c++) {
        eV[c] = __builtin_amdgcn_exp2f(bA[c] + NEARV*sA[c]);
        kV[c] = __builtin_amdgcn_exp2f(sA[c]*STEPV);
    }
    e00 = eV[0];

    // ---- phase 1: coarse march, zero exp2, no trans on carried chain ----
    float T = 1.0f, S = 0.0f;
    float a0 = 0.0f, a1 = 0.0f, a2 = 0.0f;
    #pragma unroll 4
    for (int p = 0; p < PTS; p++) {
        float e0c = fminf(eV[0], ECLAMP);
        float r0 = __builtin_amdgcn_rcpf(1.0f + e0c);  // op
        float m0 = e0c * r0;                           // 1-op, off-chain
        float v0 = __builtin_amdgcn_rcpf(1.0f + eV[1]);
        float v1 = __builtin_amdgcn_rcpf(1.0f + eV[2]);
        float v2 = __builtin_amdgcn_rcpf(1.0f + eV[3]);
        eV[0] *= kV[0];
        eV[1] *= kV[1];
        eV[2] *= kV[2];
        eV[3] *= kV[3];
        float w  = r0 * T;
        a0 = fmaf(w, v0, a0);
        a1 = fmaf(w, v1, a1);
        a2 = fmaf(w, v2, a2);
        S += w + 1e-5f;
        T *= m0;                                       // chain: one v_mul
    }
    out[(b*3+0)*65536 + n] = a0;
    out[(b*3+1)*65536 + n] = a1;
    out[(b*3+2)*65536 + n] = a2;

    // ---- phase 2: branchless sampling machine, zero exp2, speculative opn --
    // invariant: opn == rcp(1 + eP), maintained by selecting the precomputed
    // speculative value instead of recomputing (rcp leaves the carried chain).
    float Sinv = __builtin_amdgcn_rcpf(S);
    float op0  = __builtin_amdgcn_rcpf(1.0f + e00);    // sigmoid at d = NEAR
    float T2   = 1.0f - op0;
    float c_lo = 0.0f;
    float c_hi = (op0 + 1e-5f) * Sinv;                 // cdf[0]
    int ind = 0, kk = 1;
    float bin_prev = NEARV;                            // bin_0 == NEAR always
    float eP  = e00 * kV[0];                           // index m = 1
    float opn = __builtin_amdgcn_rcpf(1.0f + eP);
    #pragma unroll 2
    for (int it = 0; it < 2*PTS; it++) {
        float eP2  = eP * kV[0];                       // speculative advance
        float opnB = __builtin_amdgcn_rcpf(1.0f + eP2);// off-chain rcp
        float u = (float)kk * 0.015625f;               // exact k/64
        bool adv = (ind < PTS) && (c_hi <= u);         // searchsorted 'right'
        float wn  = opn * T2;
        float d0  = fmaf((float)(ind - 1), STEPV, NEARV);
        float den = c_hi - c_lo;
        den = (den < 1e-8f) ? 1.0f : den;              // ref guard
        float t = (u - c_lo) * __builtin_amdgcn_rcpf(den);
        t = fminf(fmaxf(t, 0.0f), 1.0f);
        float bin = fmaf(t, STEPV, d0);
        bin = (ind <= 0)   ? NEARV : bin;
        bin = (ind >= PTS) ? FAR63 : bin;
        float fdep = 0.5f * (bin_prev + bin);
        int widx = adv ? PTS : min(kk - 1, PTS);       // pad row on advance
        fd[widx][tid] = fdep;                          // unconditional ds_write
        float nc_hi = c_hi + (wn + 1e-5f) * Sinv;
        float nT2   = T2 * (1.0f - opn);
        bool advm   = adv && (ind < 62);               // m=min(ind+1,63) moves
        c_lo     = adv ? c_hi : c_lo;
        c_hi     = adv ? nc_hi : c_hi;
        T2       = adv ? nT2 : T2;
        bin_prev = adv ? bin_prev : bin;
        eP  = advm ? eP2  : eP;
        opn = advm ? opnB : opn;                       // select, not recompute
        ind += adv ? 1 : 0;
        kk  += adv ? 0 : 1;
    }

    // ---- phase 3: branchless merge, no trans on carried chain ----
    float T3 = 1.0f, sw = 0.0f;
    float f0 = 0.0f, f1 = 0.0f, f2 = 0.0f;
    float rd = 0.0f;
    int pc = 0, pf = 0;
    float dc = NEARV;
    float cur = fd[0][tid], nxt = fd[1][tid];
    #pragma unroll 2
    for (int it = 0; it < 2*PTS; it++) {
        float dfv = (pf < PTS) ? cur : 3.0e38f;
        bool tc = (pc < PTS) && (dc <= dfv);           // ties -> coarse (stable)
        float d = tc ? dc : dfv;
        pc += tc ? 1 : 0;
        dc = fmaf((float)pc, STEPV, NEARV);
        pf += tc ? 0 : 1;
        cur = tc ? cur : nxt;
        nxt = fd[min(pf + 1, PTS)][tid];               // unconditional ds_read
        float e0 = __builtin_amdgcn_exp2f(bA[0] + d*sA[0]);
        float e1 = __builtin_amdgcn_exp2f(bA[1] + d*sA[1]);
        float e2 = __builtin_amdgcn_exp2f(bA[2] + d*sA[2]);
        float e3 = __builtin_amdgcn_exp2f(bA[3] + d*sA[3]);
        float e0c = fminf(e0, ECLAMP);
        float r0 = __builtin_amdgcn_rcpf(1.0f + e0c);  // op
        float m0 = e0c * r0;                           // 1-op, off-chain
        float v0 = __builtin_amdgcn_rcpf(1.0f + e1);
        float v1 = __builtin_amdgcn_rcpf(1.0f + e2);
        float v2 = __builtin_amdgcn_rcpf(1.0f + e3);
        float w  = r0 * T3;
        f0 = fmaf(w, v0, f0);
        f1 = fmaf(w, v1, f1);
        f2 = fmaf(w, v2, f2);
        sw += w;
        rd = fmaf(w, d, rd);
        T3 *= m0;                                      // chain: one v_mul
    }

    out[393216 + (b*3+0)*65536 + n] = f0;
    out[393216 + (b*3+1)*65536 + n] = f1;
    out[393216 + (b*3+2)*65536 + n] = f2;
    float fop  = fminf(fmaxf(sw, 0.0f), 1.0f);
    float rdep = rd + (1.0f - fop) * 2.0f;             // d_all.max() == 2.0 exactly
    out[786432 + r] = rdep;

    unsigned ub  = __float_as_uint(rdep);              // rdep>0: u32 order == float order
    unsigned kmn = ub;
    unsigned kmx = ~ub;
    #pragma unroll
    for (int m = 32; m >= 1; m >>= 1) {
        unsigned omn = (unsigned)__shfl_xor((int)kmn, m, 64);
        unsigned omx = (unsigned)__shfl_xor((int)kmx, m, 64);
        kmn = (omn < kmn) ? omn : kmn;
        kmx = (omx < kmx) ? omx : kmx;
    }
    if (tid == 0) {
        bmm[2*blockIdx.x + 0] = kmn;                   // plain stores: no init,
        bmm[2*blockIdx.x + 1] = kmx;                   // no atomics, replay-safe
    }
}

__global__ __launch_bounds__(256) void nerf_norm(float* __restrict__ out,
                                                 const unsigned int* __restrict__ bmm)
{
    const int tid = threadIdx.x;
    // reduce 2048 per-block pairs (16KB, L2-resident broadcast)
    unsigned kmn = 0xFFFFFFFFu, kmx = 0xFFFFFFFFu;
    const uint2* bm2 = (const uint2*)bmm;
    #pragma unroll
    for (int t = 0; t < 8; t++) {
        uint2 p = bm2[tid + 256*t];
        kmn = min(kmn, p.x);
        kmx = min(kmx, p.y);
    }
    #pragma unroll
    for (int m = 32; m >= 1; m >>= 1) {
        unsigned omn = (unsigned)__shfl_xor((int)kmn, m, 64);
        unsigned omx = (unsigned)__shfl_xor((int)kmx, m, 64);
        kmn = (omn < kmn) ? omn : kmn;
        kmx = (omx < kmx) ? omx : kmx;
    }
    __shared__ unsigned smn[4], smx[4];
    if ((tid & 63) == 0) { smn[tid >> 6] = kmn; smx[tid >> 6] = kmx; }
    __syncthreads();
    kmn = min(min(smn[0], smn[1]), min(smn[2], smn[3]));
    kmx = min(min(smx[0], smx[1]), min(smx[2], smx[3]));
    float mn = __uint_as_float(kmn);
    float mx = __uint_as_float(~kmx);
    int idx = blockIdx.x * 256 + tid;
    float v = out[786432 + idx];
    out[786432 + idx] = (v - mn) * __builtin_amdgcn_rcpf(mx - mn);
}

extern "C" void kernel_launch(void* const* d_in, const int* in_sizes, int n_in,
                              void* d_out, int out_size, void* d_ws, size_t ws_size,
                              hipStream_t stream) {
    (void)in_sizes; (void)n_in; (void)out_size; (void)ws_size;
    const float* tm = (const float*)d_in[0];
    const float* wq = (const float*)d_in[1];
    float* out = (float*)d_out;
    unsigned int* bmm = (unsigned int*)d_ws;           // 2048 pairs = 16KB
    nerf_main<<<NRAYS/NT, NT, 0, stream>>>(tm, wq, out, bmm);
    nerf_norm<<<NRAYS/256, 256, 0, stream>>>(out, bmm);
}